// Round 10
// baseline (86.993 us; speedup 1.0000x reference)
//
#include <hip/hip_runtime.h>

// ReflectionRayTracer: 8192 rays x 2048 quad surfaces. out[ray][surf] = t*mask.
//
// R10: marching-window write order. R5-R9 pinned effective write BW at
// ~2.97 TB/s across width/NT/occupancy/fusion/per-block-stream-locality —
// exactly HALF the harness fill's 5.96 TB/s. Remaining difference: the fill is
// a grid-stride sweep (the whole GPU writes one contiguous few-MiB window that
// marches linearly -> long same-DRAM-row runs per HBM channel), while all my
// kernels had per-block private streams (instantaneous global footprint =
// all 64 MiB -> row-buffer thrash -> ~half BW).
// Change from R7 (ONLY the iteration order): ray = blockIdx.y + 512*i.
// At step i, the 512 row-blocks collectively write rows [512i, 512i+512) =
// one contiguous 4-MiB window sweeping the output linearly. Same math, same
// coalescing (512-B dwordx2 per wave), pure permutation of work ->
// bit-identical output, absmax must be exactly 4.03125.
// Occupancy/register layout identical to R7: SPT=2 (26 coeff floats, fits
// 64 VGPR), __launch_bounds__(256,8), grid (4,512) = 2048 blocks = 8/CU.

#define N_RAYS 8192
#define N_SURF 2048
constexpr int SPT = 2;    // surfaces per thread
constexpr int NRB = 512;  // row-blocks; rays per block = 8192/512 = 16
constexpr int RPT = N_RAYS / NRB;  // 16 iterations

__device__ __forceinline__ float safef(float x) {
    return (x == 0.0f) ? 1e-18f : x;   // jnp.where(x==0, EPS, x)
}

struct Coeffs {
    float vx, vy, vz, k;          // plane
    float g0, g1, g2;             // gam   = g  . r
    float bb0, bb1, bb2;          // beta  = bb . r
    float aa0, aa1, aa2;          // alpha = aa . r
};

__device__ __forceinline__ Coeffs surface_coeffs(const float* __restrict__ V, int s)
{
    const float4 p0 = *(const float4*)(V + (size_t)s * 12);
    const float4 p1 = *(const float4*)(V + (size_t)s * 12 + 4);
    const float4 p2 = *(const float4*)(V + (size_t)s * 12 + 8);
    const float ax = p0.x, ay = p0.y, az = p0.z;       // a = V[s][0]
    const float bx = p0.w, by = p1.x, bz = p1.y;       // b = V[s][1]
    const float cx = p1.z, cy = p1.w, cz = p2.x;       // c = V[s][2]
    const float wx = p2.y, wy = p2.z, wz = p2.w;       // V[s][3]

    // Plane: v = normalize(cross(b-a, c-a)); k = -dot(v, V[s][3])
    const float e0x = bx - ax, e0y = by - ay, e0z = bz - az;
    const float e1x = cx - ax, e1y = cy - ay, e1z = cz - az;
    const float nx = e0y * e1z - e0z * e1y;
    const float ny = e0z * e1x - e0x * e1z;
    const float nz = e0x * e1y - e0y * e1x;
    const float rn = __builtin_amdgcn_rsqf(fmaf(nx, nx, fmaf(ny, ny, nz * nz)));
    const float vx = nx * rn, vy = ny * rn, vz = nz * rn;
    const float k = -fmaf(vx, wx, fmaf(vy, wy, vz * wz));

    // Reference constants:
    const float B  = ax * bz - az * bx;
    const float D  = ax * by - ay * bx;                 // G == D
    const float E  = ax * cz - az * cx;
    const float P  = ay * cx - ax * cy;
    const float F  = B * P;
    const float rden = __builtin_amdgcn_rcpf(safef(D * fmaf(E, D, F)));
    const float rD   = __builtin_amdgcn_rcpf(safef(D));
    const float rAX  = __builtin_amdgcn_rcpf(safef(ax));

    Coeffs c;
    c.vx = vx; c.vy = vy; c.vz = vz; c.k = k;
    const float DB = D * B, DD = D * D;
    c.g0 = (DB * ay - DD * az) * rden;
    c.g1 = -(DB * ax) * rden;
    c.g2 = (DD * ax) * rden;
    const float bp = P * rD;
    c.bb0 = fmaf(bp, c.g0, -ay * rD);
    c.bb1 = fmaf(bp, c.g1,  ax * rD);
    c.bb2 = bp * c.g2;
    const float ab = -bx * rAX, ac = -cx * rAX;
    c.aa0 = fmaf(ab, c.bb0, fmaf(ac, c.g0, rAX));
    c.aa1 = fmaf(ab, c.bb1, ac * c.g1);
    c.aa2 = fmaf(ab, c.bb2, ac * c.g2);
    return c;
}

__device__ __forceinline__ float trace_pair(
    const Coeffs& c, float o0, float o1, float o2, float d0, float d1, float d2)
{
    const float vo_k = fmaf(o0, c.vx, fmaf(o1, c.vy, fmaf(o2, c.vz, c.k)));  // k + v.o
    const float vd   = fmaf(d0, c.vx, fmaf(d1, c.vy, d2 * c.vz));
    const float t    = -vo_k * __builtin_amdgcn_rcpf(vd);

    const float rx = fmaf(t, d0, o0);
    const float ry = fmaf(t, d1, o1);
    const float rz = fmaf(t, d2, o2);

    const float gam   = fmaf(c.g0,  rx, fmaf(c.g1,  ry, c.g2  * rz));
    const float beta  = fmaf(c.bb0, rx, fmaf(c.bb1, ry, c.bb2 * rz));
    const float alpha = fmaf(c.aa0, rx, fmaf(c.aa1, ry, c.aa2 * rz));

    const float mn = fminf(fminf(beta, gam), alpha);   // v_min3_f32
    return (mn > 0.0f) ? t : 0.0f;
}

__global__ __launch_bounds__(256, 8) void trace_kernel(
    const float* __restrict__ o, const float* __restrict__ dr,
    const float* __restrict__ V, float* __restrict__ out)
{
    const int s0 = (blockIdx.x * 256 + threadIdx.x) * SPT;  // 2 consecutive surfaces

    const Coeffs ca = surface_coeffs(V, s0);
    const Coeffs cb = surface_coeffs(V, s0 + 1);

    const int yb = blockIdx.y;    // 0..511
#pragma unroll 4
    for (int i = 0; i < RPT; ++i) {
        const int ray = yb + NRB * i;   // marching window: step i covers rows [512i, 512i+512)
        // Block-uniform ray loads -> scalar loads.
        const float o0 = o[ray * 3 + 0], o1 = o[ray * 3 + 1], o2 = o[ray * 3 + 2];
        const float d0 = dr[ray * 3 + 0], d1 = dr[ray * 3 + 1], d2 = dr[ray * 3 + 2];

        float2 res;
        res.x = trace_pair(ca, o0, o1, o2, d0, d1, d2);
        res.y = trace_pair(cb, o0, o1, o2, d0, d1, d2);
        *(float2*)(out + (size_t)ray * N_SURF + s0) = res;   // 8B-aligned dwordx2
    }
}

extern "C" void kernel_launch(void* const* d_in, const int* in_sizes, int n_in,
                              void* d_out, int out_size, void* d_ws, size_t ws_size,
                              hipStream_t stream) {
    const float* o  = (const float*)d_in[0];
    const float* dr = (const float*)d_in[1];
    const float* V  = (const float*)d_in[2];
    float* out = (float*)d_out;

    trace_kernel<<<dim3(N_SURF / (256 * SPT), NRB), dim3(256), 0, stream>>>(o, dr, V, out);
}